// Round 4
// baseline (441.611 us; speedup 1.0000x reference)
//
#include <hip/hip_runtime.h>

#define C 256
#define K_TRUNC 80
#define NG (K_TRUNC / 4)             // 20 init groups (4 atoms each)
#define N_ATOMS 16384
#define SLOPE 0.2f
#define NFIN 32
#define NWG (7 + NFIN)               // 39 workgroups

__device__ __forceinline__ float lrelu(float x) { return x >= 0.f ? x : SLOPE * x; }

// ---- workspace layout (float offsets) ----
#define OFF_LV    0
#define OFF_P0    (256)
#define OFF_H     (OFF_P0 + K_TRUNC * C)          // hbuf[4][K][C]
#define OFF_PIH   (OFF_H + 4 * K_TRUNC * C)       // pih[3][K][C]
#define OFF_PARTS (OFF_PIH + 3 * K_TRUNC * C)     // partsbuf[32][C]
#define OFF_FLAGS (OFF_PARTS + NFIN * C)          // int flags, stride-32 padded
// flag slots (each 128B apart): 0..3 h-layer step ctr; 4..6 ih ctr;
// 8..27 init-group done(==1); 28 len done(==1); 32..63 fin-done(==1)
#define FLG(f, i) ((f)[(i) << 5])

__device__ __forceinline__ int aload(int* p) {
    return __hip_atomic_load(p, __ATOMIC_ACQUIRE, __HIP_MEMORY_SCOPE_AGENT);
}
__device__ __forceinline__ void astore(int* p, int v) {
    __hip_atomic_store(p, v, __ATOMIC_RELEASE, __HIP_MEMORY_SCOPE_AGENT);
}

// ---------------------------------------------------------------------------
__device__ __forceinline__ float4 matvec_lds(const float4* __restrict__ wreg,
                                             const float* __restrict__ vec, int rb) {
    const float4* vp = (const float4*)(vec + rb * 16);   // wave-uniform broadcast
    float4 v0 = vp[0], v1 = vp[1], v2 = vp[2], v3 = vp[3];
    float vv[16] = {v0.x, v0.y, v0.z, v0.w, v1.x, v1.y, v1.z, v1.w,
                    v2.x, v2.y, v2.z, v2.w, v3.x, v3.y, v3.z, v3.w};
    float4 acc = {0.f, 0.f, 0.f, 0.f};
    #pragma unroll
    for (int r = 0; r < 16; ++r) {
        acc.x += vv[r] * wreg[r].x;
        acc.y += vv[r] * wreg[r].y;
        acc.z += vv[r] * wreg[r].z;
        acc.w += vv[r] * wreg[r].w;
    }
    return acc;
}

__device__ __forceinline__ float4 matvec_reg(const float4* __restrict__ wreg,
                                             float4 v0, float4 v1, float4 v2, float4 v3) {
    float vv[16] = {v0.x, v0.y, v0.z, v0.w, v1.x, v1.y, v1.z, v1.w,
                    v2.x, v2.y, v2.z, v2.w, v3.x, v3.y, v3.z, v3.w};
    float4 acc = {0.f, 0.f, 0.f, 0.f};
    #pragma unroll
    for (int r = 0; r < 16; ++r) {
        acc.x += vv[r] * wreg[r].x;
        acc.y += vv[r] * wreg[r].y;
        acc.z += vv[r] * wreg[r].z;
        acc.w += vv[r] * wreg[r].w;
    }
    return acc;
}

// init-MLP pass for one 4-atom group: yin[C*4] -> (act? lrelu) -> yin or gout.
// Only tid<256 compute; full-WG barriers inside. partP = 4*1040 floats (padded).
__device__ __forceinline__ void init_pass(const float* __restrict__ W,
                                          const float* __restrict__ bias, bool act,
                                          float* __restrict__ gout, int tbase,
                                          float* __restrict__ yin,
                                          float* __restrict__ partP, int tid) {
    if (tid < 256) {
        const int g = tid & 63, rb = tid >> 6;
        float4 a0 = {0,0,0,0}, a1 = {0,0,0,0}, a2 = {0,0,0,0}, a3 = {0,0,0,0};
        #pragma unroll 8
        for (int ii = 0; ii < 64; ++ii) {
            const int row = rb * 64 + ii;
            float4 wv = *(const float4*)(W + (size_t)row * C + 4 * g);
            float4 yv = *(const float4*)(yin + row * 4);   // broadcast
            a0.x += wv.x * yv.x; a0.y += wv.x * yv.y; a0.z += wv.x * yv.z; a0.w += wv.x * yv.w;
            a1.x += wv.y * yv.x; a1.y += wv.y * yv.y; a1.z += wv.y * yv.z; a1.w += wv.y * yv.w;
            a2.x += wv.z * yv.x; a2.y += wv.z * yv.y; a2.z += wv.z * yv.z; a2.w += wv.z * yv.w;
            a3.x += wv.w * yv.x; a3.y += wv.w * yv.y; a3.z += wv.w * yv.z; a3.w += wv.w * yv.w;
        }
        const int c0 = 4 * g, base = rb * 1040;
        // partP[rb][atom][col] padded 260 -> 4-way conflicts only
        partP[base + 0*260 + c0+0] = a0.x; partP[base + 1*260 + c0+0] = a0.y;
        partP[base + 2*260 + c0+0] = a0.z; partP[base + 3*260 + c0+0] = a0.w;
        partP[base + 0*260 + c0+1] = a1.x; partP[base + 1*260 + c0+1] = a1.y;
        partP[base + 2*260 + c0+1] = a1.z; partP[base + 3*260 + c0+1] = a1.w;
        partP[base + 0*260 + c0+2] = a2.x; partP[base + 1*260 + c0+2] = a2.y;
        partP[base + 2*260 + c0+2] = a2.z; partP[base + 3*260 + c0+2] = a2.w;
        partP[base + 0*260 + c0+3] = a3.x; partP[base + 1*260 + c0+3] = a3.y;
        partP[base + 2*260 + c0+3] = a3.z; partP[base + 3*260 + c0+3] = a3.w;
    }
    __syncthreads();
    if (tid < 256) {
        #pragma unroll
        for (int a = 0; a < 4; ++a) {
            float s = partP[0*1040 + a*260 + tid] + partP[1*1040 + a*260 + tid]
                    + partP[2*1040 + a*260 + tid] + partP[3*1040 + a*260 + tid];
            if (bias) s += bias[tid];
            if (act)  s = lrelu(s);
            if (gout) gout[(size_t)(tbase + a) * C + tid] = s;
            else      yin[tid * 4 + a] = s;
        }
    }
    __syncthreads();
}

// ===========================================================================
// THE kernel: 39 WGs x 1024.  WGs 0..6 = RNN pipeline; WGs 7..38 = fin helpers
// (+20 of them do one init group first, one does the length stack).
// ===========================================================================
__global__ __launch_bounds__(1024, 4) void mega_kernel(
        const float* __restrict__ x,
        const float* __restrict__ l,
        const float* __restrict__ lw0, const float* __restrict__ lb0,
        const float* __restrict__ lw1, const float* __restrict__ lb1,
        const float* __restrict__ lw2, const float* __restrict__ lb2,
        const float* __restrict__ iw0, const float* __restrict__ ib0,
        const float* __restrict__ iw1, const float* __restrict__ ib1,
        const float* __restrict__ iw2, const float* __restrict__ ib2,
        const float* __restrict__ iw3, const float* __restrict__ ib3,
        const float* __restrict__ wih, const float* __restrict__ whh,
        const float* __restrict__ bih, const float* __restrict__ bhh,
        const float* __restrict__ fw0, const float* __restrict__ fb0,
        const float* __restrict__ fw1, const float* __restrict__ fb1,
        const float* __restrict__ fw2, const float* __restrict__ fb2,
        const float* __restrict__ fw3, const float* __restrict__ fb3,
        float* __restrict__ ws, float* __restrict__ out) {
    __shared__ __align__(16) float vec[C];
    __shared__ __align__(16) float part[16 * 260];   // rnn: [16][256]; init: [4][4][260]
    __shared__ __align__(16) float bsum[C];
    __shared__ __align__(16) float yin[C * 4];
    __shared__ float xs[40];

    float* lv      = ws + OFF_LV;
    float* p0      = ws + OFF_P0;
    float* hbuf    = ws + OFF_H;
    float* pihbuf  = ws + OFF_PIH;
    float* partsbuf= ws + OFF_PARTS;
    int*   flags   = (int*)(ws + OFF_FLAGS);

    const int tid = threadIdx.x;
    const int b = blockIdx.x;

    if (b < 7) {
        // ================= RNN pipeline WG =================
        const int g = tid & 63;          // cols 4g..4g+3
        const int rb = tid >> 6;         // rows 16rb..16rb+15 (wave id)
        const int layer = (b + 1) >> 1;
        const bool is_ih = (b & 1) == 1;

        const float* W = (is_ih ? wih : whh) + (size_t)layer * C * C;
        float4 wreg[16];
        #pragma unroll
        for (int r = 0; r < 16; ++r)
            wreg[r] = *(const float4*)(W + (size_t)(rb * 16 + r) * C + 4 * g);
        {   // pin weights in VGPRs (128-reg cap via __launch_bounds__(1024,4))
            float* wf = (float*)wreg;
            #pragma unroll
            for (int i = 0; i < 64; ++i) asm volatile("" : "+v"(wf[i]));
        }

        if (!is_ih && tid < C) {
            bsum[tid] = bih[layer * C + tid] + bhh[layer * C + tid];
            vec[tid] = 0.f;                       // h_l(-1) = 0
        }
        __syncthreads();

        if (!is_ih) {
            // h-role: h_l(t) = relu(whh^T h_l(t-1) + p(t) + biases)
            for (int t = 0; t < K_TRUNC; ++t) {
                int* pf = (layer == 0) ? &FLG(flags, 8 + (t >> 2)) : &FLG(flags, 4 + layer - 1);
                const int need = (layer == 0) ? 1 : (t + 1);
                const float* psrc = (layer == 0)
                    ? (p0 + (size_t)t * C)
                    : (pihbuf + ((size_t)(layer - 1) * K_TRUNC + t) * C);
                float pv = 0.f; bool rdy = true;
                if (tid < C) {                    // early check + speculative load
                    rdy = (aload(pf) >= need);
                    if (rdy) pv = psrc[tid];
                }
                float4 acc = matvec_lds(wreg, vec, rb);
                *(float4*)(part + rb * C + 4 * g) = acc;
                if (tid < C && !rdy) {
                    while (aload(pf) < need) __builtin_amdgcn_s_sleep(1);
                    pv = psrc[tid];
                }
                __syncthreads();
                if (tid < C) {
                    float s = pv + bsum[tid];
                    #pragma unroll
                    for (int q = 0; q < 16; ++q) s += part[q * C + tid];
                    s = fmaxf(s, 0.f);
                    vec[tid] = s;
                    hbuf[((size_t)layer * K_TRUNC + t) * C + tid] = s;
                }
                __syncthreads();
                if (tid == 0) astore(&FLG(flags, layer), t + 1);
            }
        } else {
            // ih-role with 1-step lookahead: pih_l(t) = wih^T h_{l-1}(t)
            int* srcflag = &FLG(flags, layer - 1);
            int* myflag  = &FLG(flags, 4 + layer - 1);
            const float* hsrc = hbuf + (size_t)(layer - 1) * K_TRUNC * C;
            while (aload(srcflag) < 1) __builtin_amdgcn_s_sleep(1);
            const float4* hp = (const float4*)(hsrc + rb * 16);
            float4 c0 = hp[0], c1 = hp[1], c2 = hp[2], c3 = hp[3];
            for (int t = 0; t < K_TRUNC; ++t) {
                float4 n0, n1, n2, n3; bool nrdy = false;
                if (t + 1 < K_TRUNC) {
                    nrdy = (aload(srcflag) >= t + 2);
                    if (nrdy) {
                        const float4* np = (const float4*)(hsrc + (size_t)(t + 1) * C + rb * 16);
                        n0 = np[0]; n1 = np[1]; n2 = np[2]; n3 = np[3];
                    }
                }
                float4 acc = matvec_reg(wreg, c0, c1, c2, c3);
                *(float4*)(part + rb * C + 4 * g) = acc;
                __syncthreads();
                if (tid < C) {
                    float s = 0.f;
                    #pragma unroll
                    for (int q = 0; q < 16; ++q) s += part[q * C + tid];
                    pihbuf[((size_t)(layer - 1) * K_TRUNC + t) * C + tid] = s;
                }
                __syncthreads();
                if (tid == 0) astore(myflag, t + 1);
                if (t + 1 < K_TRUNC) {
                    if (!nrdy) {
                        while (aload(srcflag) < t + 2) __builtin_amdgcn_s_sleep(1);
                        const float4* np = (const float4*)(hsrc + (size_t)(t + 1) * C + rb * 16);
                        n0 = np[0]; n1 = np[1]; n2 = np[2]; n3 = np[3];
                    }
                    c0 = n0; c1 = n1; c2 = n2; c3 = n3;
                }
            }
        }
        return;
    }

    // ================= fin helper WG =================
    const int w = b - 7;                  // 0..31
    const int sub = tid >> 8;             // 0..3
    const int j = tid & 255;

    if (w >= 12) {
        // ---- init group g2 = w-12: atoms [base, base+4) of truncated window ----
        const int g2 = w - 12;
        const int atom0 = (N_ATOMS - K_TRUNC) + g2 * 4;
        if (tid < 40) xs[tid] = x[(size_t)atom0 * 10 + tid];
        __syncthreads();
        if (tid < 256) {
            float wv[10];
            #pragma unroll
            for (int i = 0; i < 10; ++i) wv[i] = iw0[i * C + tid];
            #pragma unroll
            for (int a = 0; a < 4; ++a) {
                float acc = ib0[tid];
                #pragma unroll
                for (int i = 0; i < 10; ++i) acc += xs[a * 10 + i] * wv[i];
                yin[tid * 4 + a] = lrelu(acc);
            }
        }
        __syncthreads();
        init_pass(iw1, ib1, true,  nullptr, 0, yin, part, tid);
        init_pass(iw2, ib2, true,  nullptr, 0, yin, part, tid);
        init_pass(iw3, ib3, false, nullptr, 0, yin, part, tid);
        init_pass(wih, nullptr, false, p0, g2 * 4, yin, part, tid);  // wih layer 0
        if (tid == 0) astore(&FLG(flags, 8 + g2), 1);
    } else if (w == 11) {
        // ---- length stack ----
        if (tid < 256) vec[tid] = lrelu(l[0] * lw0[tid] + lb0[tid]);
        __syncthreads();
        if (tid < 256) {
            float acc = lb1[tid];
            #pragma unroll 8
            for (int i = 0; i < C; ++i) acc += vec[i] * lw1[i * C + tid];
            bsum[tid] = lrelu(acc);
        }
        __syncthreads();
        if (tid < 256) {
            float acc = lb2[tid];
            #pragma unroll 8
            for (int i = 0; i < C; ++i) acc += bsum[i] * lw2[i * C + tid];
            lv[tid] = acc;
        }
        __syncthreads();
        if (tid == 0) astore(&FLG(flags, 28), 1);
    }

    // ---- preload fw0 slice into regs; w==0 warms fw1/fw2 into its L2 ----
    const int rlo = w * 40;
    const int r0 = rlo + sub * 10;
    float wrow[10];
    #pragma unroll
    for (int i = 0; i < 10; ++i) wrow[i] = fw0[(size_t)(r0 + i) * C + j];
    #pragma unroll
    for (int i = 0; i < 10; ++i) asm volatile("" : "+v"(wrow[i]));
    if (w == 0) {
        float dummy = 0.f;
        #pragma unroll
        for (int i = 0; i < 16; ++i) {
            float4 t1 = *(const float4*)(fw1 + (size_t)(tid + i * 1024) * 4);
            float4 t2 = *(const float4*)(fw2 + (size_t)(tid + i * 1024) * 4);
            dummy += t1.x + t1.y + t1.z + t1.w + t2.x + t2.y + t2.z + t2.w;
        }
        asm volatile("" :: "v"(dummy));
    }

    // ---- wait for sources of our 40 rows ----
    if (tid == 0) {
        if (rlo < 256)
            while (aload(&FLG(flags, 28)) != 1) __builtin_amdgcn_s_sleep(8);
        if (rlo + 39 >= 256) {
            const int l0 = (rlo >= 256) ? ((rlo - 256) >> 8) : 0;
            const int l1 = (rlo + 39 - 256) >> 8;
            for (int ly = l0; ly <= l1; ++ly)
                while (aload(&FLG(flags, ly)) < K_TRUNC) __builtin_amdgcn_s_sleep(8);
        }
    }
    __syncthreads();

    // ---- partial of feat @ fw0 over rows [rlo, rlo+40) ----
    float acc = 0.f;
    #pragma unroll
    for (int i = 0; i < 10; ++i) {
        const int r = r0 + i;
        const float fv = (r < 256)
            ? lv[r]
            : hbuf[(((size_t)((r - 256) >> 8)) * K_TRUNC + (K_TRUNC - 1)) * C + ((r - 256) & 255)];
        acc += fv * wrow[i];
    }
    part[sub * C + j] = acc;
    __syncthreads();
    if (tid < C)
        partsbuf[(size_t)w * C + tid] =
            part[tid] + part[C + tid] + part[2 * C + tid] + part[3 * C + tid];
    __syncthreads();
    if (tid == 0) astore(&FLG(flags, 32 + w), 1);
    if (w != 0) return;

    // ---- tail (WG 7 / w==0): z = lrelu(sum parts + b0) -> w1 -> w2 -> w3 ----
    if (tid == 0)
        for (int q = 1; q < NFIN; ++q)
            while (aload(&FLG(flags, 32 + q)) != 1) __builtin_amdgcn_s_sleep(1);
    __syncthreads();
    if (tid < C) {
        float s = partsbuf[tid];
        #pragma unroll 8
        for (int q = 1; q < NFIN; ++q) s += partsbuf[(size_t)q * C + tid];
        vec[tid] = lrelu(s + fb0[tid]);
    }
    __syncthreads();
    acc = 0.f;
    #pragma unroll 8
    for (int i = 0; i < 64; ++i) {
        const int r = sub * 64 + i;
        acc += vec[r] * fw1[(size_t)r * C + j];
    }
    part[sub * C + j] = acc;
    __syncthreads();
    if (tid < C)
        bsum[tid] = lrelu(part[tid] + part[C + tid] + part[2 * C + tid] + part[3 * C + tid] + fb1[tid]);
    __syncthreads();
    acc = 0.f;
    #pragma unroll 8
    for (int i = 0; i < 64; ++i) {
        const int r = sub * 64 + i;
        acc += bsum[r] * fw2[(size_t)r * C + j];
    }
    part[sub * C + j] = acc;
    __syncthreads();
    if (tid < C)
        vec[tid] = lrelu(part[tid] + part[C + tid] + part[2 * C + tid] + part[3 * C + tid] + fb2[tid]) * fw3[tid];
    __syncthreads();
    for (int st = 128; st > 0; st >>= 1) {
        if (tid < st) vec[tid] += vec[tid + st];
        __syncthreads();
    }
    if (tid == 0) out[0] = vec[0] + fb3[0];
}

// ---------------------------------------------------------------------------
extern "C" void kernel_launch(void* const* d_in, const int* in_sizes, int n_in,
                              void* d_out, int out_size, void* d_ws, size_t ws_size,
                              hipStream_t stream) {
    const float* x      = (const float*)d_in[0];
    const float* l      = (const float*)d_in[1];
    const float* len_w0 = (const float*)d_in[2];
    const float* len_b0 = (const float*)d_in[3];
    const float* len_w1 = (const float*)d_in[4];
    const float* len_b1 = (const float*)d_in[5];
    const float* len_w2 = (const float*)d_in[6];
    const float* len_b2 = (const float*)d_in[7];
    const float* init_w0 = (const float*)d_in[8];
    const float* init_b0 = (const float*)d_in[9];
    const float* init_w1 = (const float*)d_in[10];
    const float* init_b1 = (const float*)d_in[11];
    const float* init_w2 = (const float*)d_in[12];
    const float* init_b2 = (const float*)d_in[13];
    const float* init_w3 = (const float*)d_in[14];
    const float* init_b3 = (const float*)d_in[15];
    const float* rnn_wih = (const float*)d_in[16];
    const float* rnn_whh = (const float*)d_in[17];
    const float* rnn_bih = (const float*)d_in[18];
    const float* rnn_bhh = (const float*)d_in[19];
    const float* fin_w0 = (const float*)d_in[20];
    const float* fin_b0 = (const float*)d_in[21];
    const float* fin_w1 = (const float*)d_in[22];
    const float* fin_b1 = (const float*)d_in[23];
    const float* fin_w2 = (const float*)d_in[24];
    const float* fin_b2 = (const float*)d_in[25];
    const float* fin_w3 = (const float*)d_in[26];
    const float* fin_b3 = (const float*)d_in[27];

    mega_kernel<<<NWG, 1024, 0, stream>>>(
        x, l,
        len_w0, len_b0, len_w1, len_b1, len_w2, len_b2,
        init_w0, init_b0, init_w1, init_b1, init_w2, init_b2, init_w3, init_b3,
        rnn_wih, rnn_whh, rnn_bih, rnn_bhh,
        fin_w0, fin_b0, fin_w1, fin_b1, fin_w2, fin_b2, fin_w3, fin_b3,
        (float*)d_ws, (float*)d_out);
}